// Round 5
// baseline (372.144 us; speedup 1.0000x reference)
//
#include <hip/hip_runtime.h>

// SparseVoxelEncoder: trilinear interpolation of 8 corner embeddings per point.
// out[p, :] = sum_{c=0}^{7} w_c(p) * values[point_feats[sampled_idx[p]][c], :]
//
// R8: shrink the bucket-scatter region so write-allocate stops hurting.
// Ledger: 156 us fixed harness + ~122 us main + ~84 us aux (R7).
// Aux cost explained by write-allocate on 1M scattered 16-B stores over a
// 67 MB region: each cold 128-B line fetched + written back ~= 250 MB hidden
// traffic. R2-R4 + R7 proved cache hints are null on gfx950 (4/4 experiments),
// so instead make the scatter region L2-RESIDENT: id-only entries (4 B) ->
// bucket = H*8*4 = 16.8 MB + 2.1 MB counts < 32 MB aggregate L2.
//   - aux fast path: load idx, atomicAdd, store p. No xyz read (-12 MB).
//   - main gathers sampled_xyz per point (broadcast over 8 lanes); R5 ran this
//     exact gather at 127 us main -> bounded cost.
//   - main reads counts/bucket just written by aux -> MALL/L2 hits.
// Overflow (count>CAP ~ 60 points total, Poisson(2)): computed directly in the
// bucket pass, identical FLOP order -> output stays bit-exact (absmax 0).

#define VOXEL_INV 4.0f  // 1 / 0.25
#define CAP 8           // bucket slots per voxel (32 B/voxel, id-only)

typedef float vfloat4 __attribute__((ext_vector_type(4)));

// ---- shared per-point math (identical FLOP order everywhere -> bit-identical)
__device__ __forceinline__ void corner_ids(const int* __restrict__ point_feats,
                                           int vi, int* ids)
{
    const int4* pf4 = (const int4*)(point_feats + ((size_t)vi << 3));
    int4 f0 = pf4[0];
    int4 f1 = pf4[1];
    ids[0] = f0.x; ids[1] = f0.y; ids[2] = f0.z; ids[3] = f0.w;
    ids[4] = f1.x; ids[5] = f1.y; ids[6] = f1.z; ids[7] = f1.w;
}

// full 32-float row for one point, single thread (rare overflow path)
__device__ void compute_point_direct(
    const float* __restrict__ point_xyz,
    const float* __restrict__ values,
    const int*   __restrict__ point_feats,
    float*       __restrict__ out,
    int vi, int p, float sx, float sy, float sz)
{
    float cx = point_xyz[(size_t)vi * 3 + 0];
    float cy = point_xyz[(size_t)vi * 3 + 1];
    float cz = point_xyz[(size_t)vi * 3 + 2];

    float px = (sx - cx) * VOXEL_INV + 0.5f;
    float py = (sy - cy) * VOXEL_INV + 0.5f;
    float pz = (sz - cz) * VOXEL_INV + 0.5f;

    float xs[2] = {1.0f - px, px};
    float ys[2] = {1.0f - py, py};
    float zs[2] = {1.0f - pz, pz};

    int ids[8];
    corner_ids(point_feats, vi, ids);

    vfloat4 acc[8] = {};
#pragma unroll
    for (int c = 0; c < 8; ++c) {
        float w = xs[(c >> 2) & 1] * ys[(c >> 1) & 1] * zs[c & 1];
        const vfloat4* vr = (const vfloat4*)(values + ((size_t)ids[c] << 5));
#pragma unroll
        for (int k = 0; k < 8; ++k) acc[k] += w * vr[k];
    }
    vfloat4* o = (vfloat4*)(out + ((size_t)p << 5));
#pragma unroll
    for (int k = 0; k < 8; ++k) __builtin_nontemporal_store(acc[k], o + k);
}

// ---------------------------------------------------------------- direct path
__global__ __launch_bounds__(256) void svenc_direct(
    const float* __restrict__ sampled_xyz,
    const float* __restrict__ point_xyz,
    const float* __restrict__ values,
    const int*   __restrict__ sampled_idx,
    const int*   __restrict__ point_feats,
    float*       __restrict__ out,
    int P)
{
    int t   = blockIdx.x * blockDim.x + threadIdx.x;
    int pid = t >> 3;
    int sub = t & 7;
    if (pid >= P) return;

    int vi = __builtin_nontemporal_load(sampled_idx + pid);
    float sx = __builtin_nontemporal_load(sampled_xyz + pid * 3 + 0);
    float sy = __builtin_nontemporal_load(sampled_xyz + pid * 3 + 1);
    float sz = __builtin_nontemporal_load(sampled_xyz + pid * 3 + 2);

    float cx = point_xyz[(size_t)vi * 3 + 0];
    float cy = point_xyz[(size_t)vi * 3 + 1];
    float cz = point_xyz[(size_t)vi * 3 + 2];

    float px = (sx - cx) * VOXEL_INV + 0.5f;
    float py = (sy - cy) * VOXEL_INV + 0.5f;
    float pz = (sz - cz) * VOXEL_INV + 0.5f;

    float xs[2] = {1.0f - px, px};
    float ys[2] = {1.0f - py, py};
    float zs[2] = {1.0f - pz, pz};

    int ids[8];
    corner_ids(point_feats, vi, ids);

    vfloat4 acc = {0.0f, 0.0f, 0.0f, 0.0f};
#pragma unroll
    for (int c = 0; c < 8; ++c) {
        float w = xs[(c >> 2) & 1] * ys[(c >> 1) & 1] * zs[c & 1];
        const vfloat4 v = ((const vfloat4*)(values + ((size_t)ids[c] << 5)))[sub];
        acc += w * v;
    }
    __builtin_nontemporal_store(acc, (vfloat4*)(out + ((size_t)pid << 5)) + sub);
}

// --------------------------------------------------------- id-bucket scatter
__global__ __launch_bounds__(256) void k_bucket_id(
    const float* __restrict__ sampled_xyz,
    const float* __restrict__ point_xyz,
    const float* __restrict__ values,
    const int*   __restrict__ sampled_idx,
    const int*   __restrict__ point_feats,
    float*       __restrict__ out,
    int*         __restrict__ counts,
    int*         __restrict__ bucket,   // [H*CAP] point ids, 16.8 MB (L2-fit)
    int P)
{
    int p = blockIdx.x * 256 + threadIdx.x;
    if (p >= P) return;

    int vi = __builtin_nontemporal_load(sampled_idx + p);
    int pos = atomicAdd(counts + vi, 1);
    if (pos < CAP) {
        // scatter region is L2-resident -> write-allocate traffic stays on-chip
        bucket[((size_t)vi << 3) + pos] = p;
    } else {
        // rare (~60 points total): compute in-place, fully correct
        float sx = sampled_xyz[(size_t)p * 3 + 0];
        float sy = sampled_xyz[(size_t)p * 3 + 1];
        float sz = sampled_xyz[(size_t)p * 3 + 2];
        compute_point_direct(point_xyz, values, point_feats, out, vi, p, sx, sy, sz);
    }
}

// ---------------------------------------------------------------- main kernel
__global__ __launch_bounds__(256) void svenc_voxel_id(
    const float* __restrict__ sampled_xyz,
    const float* __restrict__ point_xyz,
    const float* __restrict__ values,
    const int*   __restrict__ point_feats,
    const int*   __restrict__ counts,
    const int*   __restrict__ bucket,
    float*       __restrict__ out,
    int H)
{
    int t   = blockIdx.x * 256 + threadIdx.x;
    int g   = t >> 3;       // voxel index (sequential -> streaming voxel tables)
    int sub = t & 7;        // float4 chunk of the 32-float row
    int lane = threadIdx.x & 63;
    if (g >= H) return;

    int n = counts[g];      // written by aux -> MALL/L2 hit

    // coalesced slot read: lane sub picks up slot `sub` of its voxel's bucket
    // (contiguous 4 B/lane across the wave); garbage beyond n is never used.
    int myslot = bucket[((size_t)g << 3) + sub];

    if (n == 0) return;
    if (n > CAP) n = CAP;

    float cx = point_xyz[(size_t)g * 3 + 0];
    float cy = point_xyz[(size_t)g * 3 + 1];
    float cz = point_xyz[(size_t)g * 3 + 2];

    int ids[8];
    corner_ids(point_feats, g, ids);

    // 8 corner rows loaded ONCE into registers, reused for all points in voxel
    vfloat4 v[8];
#pragma unroll
    for (int c = 0; c < 8; ++c)
        v[c] = ((const vfloat4*)(values + ((size_t)ids[c] << 5)))[sub];

    int grpbase = lane & 56;   // first lane of this voxel's 8-lane group
    for (int i = 0; i < n; ++i) {
        int p = __shfl(myslot, grpbase + i, 64);   // broadcast slot i's id

        // broadcast gather: 8 lanes read the same 12 B (merged by HW)
        float sx = sampled_xyz[(size_t)p * 3 + 0];
        float sy = sampled_xyz[(size_t)p * 3 + 1];
        float sz = sampled_xyz[(size_t)p * 3 + 2];

        float px = (sx - cx) * VOXEL_INV + 0.5f;
        float py = (sy - cy) * VOXEL_INV + 0.5f;
        float pz = (sz - cz) * VOXEL_INV + 0.5f;

        float xs[2] = {1.0f - px, px};
        float ys[2] = {1.0f - py, py};
        float zs[2] = {1.0f - pz, pz};

        vfloat4 acc = {0.0f, 0.0f, 0.0f, 0.0f};
#pragma unroll
        for (int c = 0; c < 8; ++c) {
            float w = xs[(c >> 2) & 1] * ys[(c >> 1) & 1] * zs[c & 1];
            acc += w * v[c];
        }
        __builtin_nontemporal_store(acc, (vfloat4*)(out + ((size_t)p << 5)) + sub);
    }
}

// ---------------------------------------------------------------- launcher
extern "C" void kernel_launch(void* const* d_in, const int* in_sizes, int n_in,
                              void* d_out, int out_size, void* d_ws, size_t ws_size,
                              hipStream_t stream) {
    const float* sampled_xyz = (const float*)d_in[0];
    const float* point_xyz   = (const float*)d_in[1];
    const float* values      = (const float*)d_in[2];
    const int*   sampled_idx = (const int*)d_in[3];
    const int*   point_feats = (const int*)d_in[4];
    float* out = (float*)d_out;

    int P = in_sizes[3];   // element count of sampled_idx == number of points

    // H: handle both in_sizes conventions (total elements vs first-dim).
    int H;
    if (in_sizes[0] == 3 * P)       H = in_sizes[4] / 8;
    else                            H = in_sizes[4];

    size_t bucketB = (size_t)H * CAP * 4;        // id per slot
    size_t need    = bucketB + (size_t)H * 4;    // + counts

    if (d_ws != nullptr && ws_size >= need && H > 0) {
        int* bucket = (int*)d_ws;
        int* counts = (int*)((char*)d_ws + bucketB);
        hipMemsetAsync(counts, 0, (size_t)H * 4, stream);

        int gp = (P + 255) / 256;
        k_bucket_id<<<gp, 256, 0, stream>>>(
            sampled_xyz, point_xyz, values, sampled_idx, point_feats,
            out, counts, bucket, P);

        long tt = (long)H * 8;
        int gm = (int)((tt + 255) / 256);
        svenc_voxel_id<<<gm, 256, 0, stream>>>(
            sampled_xyz, point_xyz, values, point_feats, counts, bucket, out, H);
    } else {
        long total_threads = (long)P * 8;
        int grid = (int)((total_threads + 255) / 256);
        svenc_direct<<<grid, 256, 0, stream>>>(
            sampled_xyz, point_xyz, values, sampled_idx, point_feats, out, P);
    }
}